// Round 2
// baseline (99.382 us; speedup 1.0000x reference)
//
#include <hip/hip_runtime.h>
#include <hip/hip_bf16.h>
#include <stdint.h>

#define N 4096
#define D 512
#define TILE 128
#define BK 32
#define KITERS (D / BK)   // 16
#define NB (N / TILE)     // 32

typedef __bf16 bf16x8 __attribute__((ext_vector_type(8)));
typedef float f32x4 __attribute__((ext_vector_type(4)));

// ---------------------------------------------------------------------------
// Kernel 1: fp32 -> bf16 conversion (for MFMA) + fp32 row squared-norms.
// One wave per row: 512 elems / 64 lanes = 8 elems/lane (one 16B bf16 store).
// ---------------------------------------------------------------------------
__global__ __launch_bounds__(256) void prep_kernel(const float* __restrict__ x,
                                                   __bf16* __restrict__ xb,
                                                   float* __restrict__ sq) {
    int row  = blockIdx.x * 4 + (threadIdx.x >> 6);
    int lane = threadIdx.x & 63;
    const float* xr = x + (size_t)row * D + lane * 8;
    float4 v0 = *reinterpret_cast<const float4*>(xr);
    float4 v1 = *reinterpret_cast<const float4*>(xr + 4);

    bf16x8 b;
    b[0] = (__bf16)v0.x; b[1] = (__bf16)v0.y; b[2] = (__bf16)v0.z; b[3] = (__bf16)v0.w;
    b[4] = (__bf16)v1.x; b[5] = (__bf16)v1.y; b[6] = (__bf16)v1.z; b[7] = (__bf16)v1.w;
    *reinterpret_cast<bf16x8*>(xb + (size_t)row * D + lane * 8) = b;

    float s = v0.x * v0.x + v0.y * v0.y + v0.z * v0.z + v0.w * v0.w +
              v1.x * v1.x + v1.y * v1.y + v1.z * v1.z + v1.w * v1.w;
    #pragma unroll
    for (int off = 32; off > 0; off >>= 1) s += __shfl_down(s, off);
    if (lane == 0) sq[row] = s;
}

// ---------------------------------------------------------------------------
// Kernel 2: lower-triangle Gram via bf16 MFMA + fused distance epilogue.
// 256 threads = 4 waves in 2x2; each wave owns 64x64 of the 128x128 tile.
// Double-buffered LDS: iter k issues global_load_lds for k+1 BEFORE compute,
// so the pre-barrier vmcnt(0) drain overlaps with ds_read+MFMA of iter k.
// ---------------------------------------------------------------------------
__global__ __launch_bounds__(256) void pairdist_kernel(const __bf16* __restrict__ xb,
                                                       const float* __restrict__ sq,
                                                       float* __restrict__ out) {
    __shared__ __bf16 As[2][TILE * BK];  // 2 x 8 KB
    __shared__ __bf16 Bs[2][TILE * BK];  // 2 x 8 KB

    // Linear block id -> (bi, bj) with bj <= bi (lower-triangular block pairs)
    int t  = blockIdx.x;
    int bi = (int)((sqrtf(8.0f * (float)t + 1.0f) - 1.0f) * 0.5f);
    while ((bi + 1) * (bi + 2) / 2 <= t) bi++;
    while (bi * (bi + 1) / 2 > t) bi--;
    int bj = t - bi * (bi + 1) / 2;

    int tid  = threadIdx.x;
    int w    = tid >> 6;        // wave 0..3
    int lane = tid & 63;
    int quad = lane >> 4;       // 0..3
    int lr   = lane & 15;       // 0..15
    int wm   = w >> 1;          // wave row (0..1) -> 64 rows
    int wn   = w & 1;           // wave col (0..1) -> 64 cols

    f32x4 acc[4][4];
    #pragma unroll
    for (int mt = 0; mt < 4; mt++)
        #pragma unroll
        for (int nt = 0; nt < 4; nt++)
            acc[mt][nt] = (f32x4)0.0f;

    // Staging: per global_load_lds issue, a wave loads 16 rows x 64B; the HW
    // LDS placement base + lane*16 matches [row][k] stride-64B exactly.
    int srow = lane >> 2;            // 0..15
    int scol = (lane & 3) * 8;       // bf16 elems within 32
    const __bf16* ga = xb + (size_t)(bi * TILE + w * 16 + srow) * D + scol;
    const __bf16* gb = xb + (size_t)(bj * TILE + w * 16 + srow) * D + scol;
    int ldsoff = w * 16 * BK;        // wave-uniform LDS chunk offset

#define STAGE(buf, k0)                                                        \
    do {                                                                      \
        __builtin_amdgcn_global_load_lds(                                     \
            (const __attribute__((address_space(1))) void*)(ga + (k0)),       \
            (__attribute__((address_space(3))) void*)(As[buf] + ldsoff),      \
            16, 0, 0);                                                        \
        __builtin_amdgcn_global_load_lds(                                     \
            (const __attribute__((address_space(1))) void*)(ga + (k0) + (size_t)64 * D), \
            (__attribute__((address_space(3))) void*)(As[buf] + ldsoff + 64 * BK), \
            16, 0, 0);                                                        \
        __builtin_amdgcn_global_load_lds(                                     \
            (const __attribute__((address_space(1))) void*)(gb + (k0)),       \
            (__attribute__((address_space(3))) void*)(Bs[buf] + ldsoff),      \
            16, 0, 0);                                                        \
        __builtin_amdgcn_global_load_lds(                                     \
            (const __attribute__((address_space(1))) void*)(gb + (k0) + (size_t)64 * D), \
            (__attribute__((address_space(3))) void*)(Bs[buf] + ldsoff + 64 * BK), \
            16, 0, 0);                                                        \
    } while (0)

    STAGE(0, 0);
    __syncthreads();   // vmcnt(0) drain: only the prologue pays full latency

    for (int it = 0; it < KITERS; ++it) {
        int cur = it & 1;
        if (it + 1 < KITERS) STAGE(cur ^ 1, (it + 1) * BK);

        // Fragment loads: A[m = lr][k = quad*8 + j], B[n = lr][k = quad*8 + j]
        bf16x8 af[4], bfr[4];
        #pragma unroll
        for (int mt = 0; mt < 4; mt++)
            af[mt] = *reinterpret_cast<const bf16x8*>(
                As[cur] + (wm * 64 + mt * 16 + lr) * BK + quad * 8);
        #pragma unroll
        for (int nt = 0; nt < 4; nt++)
            bfr[nt] = *reinterpret_cast<const bf16x8*>(
                Bs[cur] + (wn * 64 + nt * 16 + lr) * BK + quad * 8);

        #pragma unroll
        for (int mt = 0; mt < 4; mt++)
            #pragma unroll
            for (int nt = 0; nt < 4; nt++)
                acc[mt][nt] = __builtin_amdgcn_mfma_f32_16x16x32_bf16(
                    af[mt], bfr[nt], acc[mt][nt], 0, 0, 0);

        // One barrier per iter: separates this iter's ds_reads of buf[cur]
        // from next iter's global_load_lds writes into buf[cur], and drains
        // the prefetch issued at the top (a full compute phase in flight).
        __syncthreads();
    }
#undef STAGE

    // Epilogue: D[m][n] at lane: n = lane&15, m = quad*4 + reg  (m89/m91)
    int ibase = bi * TILE + wm * 64;
    int jbase = bj * TILE + wn * 64;

    float sqi[4][4], sqj[4];
    #pragma unroll
    for (int mt = 0; mt < 4; mt++)
        #pragma unroll
        for (int tt = 0; tt < 4; tt++)
            sqi[mt][tt] = sq[ibase + mt * 16 + quad * 4 + tt];
    #pragma unroll
    for (int nt = 0; nt < 4; nt++)
        sqj[nt] = sq[jbase + nt * 16 + lr];

    if (bi != bj) {
        // Off-diagonal block: j < (bj+1)*128 <= bi*128 <= i always -> no predicate
        #pragma unroll
        for (int mt = 0; mt < 4; mt++) {
            #pragma unroll
            for (int tt = 0; tt < 4; tt++) {
                int i = ibase + mt * 16 + quad * 4 + tt;
                unsigned rowoff = (unsigned)(i * (i - 1) / 2);
                #pragma unroll
                for (int nt = 0; nt < 4; nt++) {
                    int j = jbase + nt * 16 + lr;
                    float d2 = sqi[mt][tt] + sqj[nt] - 2.0f * acc[mt][nt][tt];
                    out[rowoff + (unsigned)j] = sqrtf(fmaxf(d2, 0.0f));
                }
            }
        }
    } else {
        #pragma unroll
        for (int mt = 0; mt < 4; mt++) {
            #pragma unroll
            for (int tt = 0; tt < 4; tt++) {
                int i = ibase + mt * 16 + quad * 4 + tt;
                unsigned rowoff = (unsigned)(i * (i - 1) / 2);
                #pragma unroll
                for (int nt = 0; nt < 4; nt++) {
                    int j = jbase + nt * 16 + lr;
                    if (j < i) {
                        float d2 = sqi[mt][tt] + sqj[nt] - 2.0f * acc[mt][nt][tt];
                        out[rowoff + (unsigned)j] = sqrtf(fmaxf(d2, 0.0f));
                    }
                }
            }
        }
    }
}

extern "C" void kernel_launch(void* const* d_in, const int* in_sizes, int n_in,
                              void* d_out, int out_size, void* d_ws, size_t ws_size,
                              hipStream_t stream) {
    const float* x = (const float*)d_in[0];
    float* out = (float*)d_out;

    // Workspace layout: [0, 4MB) bf16 copy of x; then 16KB of fp32 row norms.
    __bf16* xb = (__bf16*)d_ws;
    float* sq  = (float*)((char*)d_ws + (size_t)N * D * sizeof(__bf16));

    prep_kernel<<<N / 4, 256, 0, stream>>>(x, xb, sq);

    int nblocks = NB * (NB + 1) / 2;  // 528 lower-triangular block pairs
    pairdist_kernel<<<nblocks, 256, 0, stream>>>(xb, sq, out);
}

// Round 3
// 90.707 us; speedup vs baseline: 1.0956x; 1.0956x over previous
//
#include <hip/hip_runtime.h>
#include <hip/hip_bf16.h>
#include <stdint.h>

#define N 4096
#define D 512
#define TM 128          // block tile rows
#define TN 64           // block tile cols
#define BK 32
#define KITERS (D / BK) // 16

typedef __bf16 bf16x8 __attribute__((ext_vector_type(8)));
typedef float f32x4 __attribute__((ext_vector_type(4)));

// ---------------------------------------------------------------------------
// Kernel 1: fp32 -> bf16 conversion (for MFMA) + fp32 row squared-norms.
// One wave per row: 512 elems / 64 lanes = 8 elems/lane (one 16B bf16 store).
// ---------------------------------------------------------------------------
__global__ __launch_bounds__(256) void prep_kernel(const float* __restrict__ x,
                                                   __bf16* __restrict__ xb,
                                                   float* __restrict__ sq) {
    int row  = blockIdx.x * 4 + (threadIdx.x >> 6);
    int lane = threadIdx.x & 63;
    const float* xr = x + (size_t)row * D + lane * 8;
    float4 v0 = *reinterpret_cast<const float4*>(xr);
    float4 v1 = *reinterpret_cast<const float4*>(xr + 4);

    bf16x8 b;
    b[0] = (__bf16)v0.x; b[1] = (__bf16)v0.y; b[2] = (__bf16)v0.z; b[3] = (__bf16)v0.w;
    b[4] = (__bf16)v1.x; b[5] = (__bf16)v1.y; b[6] = (__bf16)v1.z; b[7] = (__bf16)v1.w;
    *reinterpret_cast<bf16x8*>(xb + (size_t)row * D + lane * 8) = b;

    float s = v0.x * v0.x + v0.y * v0.y + v0.z * v0.z + v0.w * v0.w +
              v1.x * v1.x + v1.y * v1.y + v1.z * v1.z + v1.w * v1.w;
    #pragma unroll
    for (int off = 32; off > 0; off >>= 1) s += __shfl_down(s, off);
    if (lane == 0) sq[row] = s;
}

// ---------------------------------------------------------------------------
// Kernel 2: lower-triangle Gram via bf16 MFMA + fused distance epilogue.
// 128x64 block tile, 4 waves each owning 64x32 (acc 4x2) -> grid 1056 blocks
// = 4224 waves = 4.1 waves/SIMD (vs 2.06 for 128x128/528), straggler overhead
// 21% vs 45%. Single-buffered LDS, m97-style two-barrier K-loop (explicit
// dbuf regressed in R2: compiler can't prove LDS disjointness -> vmcnt(0)
// before ds_reads).
// ---------------------------------------------------------------------------
__global__ __launch_bounds__(256, 4) void pairdist_kernel(const __bf16* __restrict__ xb,
                                                          const float* __restrict__ sq,
                                                          float* __restrict__ out) {
    __shared__ __bf16 As[TM * BK];  // 8 KB, row-major [row][k], stride 64B
    __shared__ __bf16 Bs[TN * BK];  // 4 KB

    // Linear block id -> (bi, bj): t = bi^2 + bi + bj, 0 <= bj <= 2*bi+1.
    // Row tile bi covers rows [128*bi, +128); col tile bj covers [64*bj, +64).
    int t  = blockIdx.x;
    int bi = (int)((sqrtf(4.0f * (float)t + 1.0f) - 1.0f) * 0.5f);
    while (bi * bi + 3 * bi + 2 <= t) bi++;
    while (bi * bi + bi > t) bi--;
    int bj = t - bi * bi - bi;
    bool full = (bj < 2 * bi);  // fully below diagonal: all j < i guaranteed

    int tid  = threadIdx.x;
    int w    = tid >> 6;        // wave 0..3
    int lane = tid & 63;
    int quad = lane >> 4;       // 0..3
    int lr   = lane & 15;       // 0..15
    int wm   = w >> 1;          // wave row (0..1) -> 64 rows
    int wn   = w & 1;           // wave col (0..1) -> 32 cols

    f32x4 acc[4][2];
    #pragma unroll
    for (int mt = 0; mt < 4; mt++)
        #pragma unroll
        for (int nt = 0; nt < 2; nt++)
            acc[mt][nt] = (f32x4)0.0f;

    // Staging: per global_load_lds issue, a wave loads 16 rows x 64B; HW LDS
    // placement base + lane*16 matches [row][k] stride-64B exactly.
    // Per iter the block stages A:128x32 (8KB) + B:64x32 (4KB) = 12 glds;
    // each wave issues 3 (2 for A halves, 1 for B).
    int srow = lane >> 2;            // 0..15
    int scol = (lane & 3) * 8;       // bf16 elems within the 32-wide row
    const __bf16* ga = xb + (size_t)(bi * TM + w * 16 + srow) * D + scol;
    const __bf16* gb = xb + (size_t)(bj * TN + w * 16 + srow) * D + scol;
    __bf16* la = As + w * 16 * BK;   // wave-uniform LDS bases
    __bf16* lb = Bs + w * 16 * BK;

    for (int k0 = 0; k0 < D; k0 += BK) {
        __syncthreads();   // prev iter's ds_reads done before overwrite
        __builtin_amdgcn_global_load_lds(
            (const __attribute__((address_space(1))) void*)(ga + k0),
            (__attribute__((address_space(3))) void*)la, 16, 0, 0);
        __builtin_amdgcn_global_load_lds(
            (const __attribute__((address_space(1))) void*)(ga + k0 + (size_t)64 * D),
            (__attribute__((address_space(3))) void*)(la + 64 * BK), 16, 0, 0);
        __builtin_amdgcn_global_load_lds(
            (const __attribute__((address_space(1))) void*)(gb + k0),
            (__attribute__((address_space(3))) void*)lb, 16, 0, 0);
        __syncthreads();   // drains vmcnt(0): staging visible

        // Fragment loads: A[m = lr][k = quad*8 + j], B[n = lr][k = quad*8 + j]
        bf16x8 af[4], bfr[2];
        #pragma unroll
        for (int mt = 0; mt < 4; mt++)
            af[mt] = *reinterpret_cast<const bf16x8*>(
                As + (wm * 64 + mt * 16 + lr) * BK + quad * 8);
        #pragma unroll
        for (int nt = 0; nt < 2; nt++)
            bfr[nt] = *reinterpret_cast<const bf16x8*>(
                Bs + (wn * 32 + nt * 16 + lr) * BK + quad * 8);

        #pragma unroll
        for (int mt = 0; mt < 4; mt++)
            #pragma unroll
            for (int nt = 0; nt < 2; nt++)
                acc[mt][nt] = __builtin_amdgcn_mfma_f32_16x16x32_bf16(
                    af[mt], bfr[nt], acc[mt][nt], 0, 0, 0);
    }

    // Epilogue: D[m][n] at lane: n = lane&15, m = quad*4 + reg  (m89/m91)
    int ibase = bi * TM + wm * 64;
    int jbase = bj * TN + wn * 32;

    float sqi[4][4], sqj[2];
    #pragma unroll
    for (int mt = 0; mt < 4; mt++)
        #pragma unroll
        for (int tt = 0; tt < 4; tt++)
            sqi[mt][tt] = sq[ibase + mt * 16 + quad * 4 + tt];
    #pragma unroll
    for (int nt = 0; nt < 2; nt++)
        sqj[nt] = sq[jbase + nt * 16 + lr];

    if (full) {
        #pragma unroll
        for (int mt = 0; mt < 4; mt++) {
            #pragma unroll
            for (int tt = 0; tt < 4; tt++) {
                int i = ibase + mt * 16 + quad * 4 + tt;
                unsigned rowoff = (unsigned)(i * (i - 1) / 2);
                #pragma unroll
                for (int nt = 0; nt < 2; nt++) {
                    int j = jbase + nt * 16 + lr;
                    float d2 = sqi[mt][tt] + sqj[nt] - 2.0f * acc[mt][nt][tt];
                    out[rowoff + (unsigned)j] = sqrtf(fmaxf(d2, 0.0f));
                }
            }
        }
    } else {
        #pragma unroll
        for (int mt = 0; mt < 4; mt++) {
            #pragma unroll
            for (int tt = 0; tt < 4; tt++) {
                int i = ibase + mt * 16 + quad * 4 + tt;
                unsigned rowoff = (unsigned)(i * (i - 1) / 2);
                #pragma unroll
                for (int nt = 0; nt < 2; nt++) {
                    int j = jbase + nt * 16 + lr;
                    if (j < i) {
                        float d2 = sqi[mt][tt] + sqj[nt] - 2.0f * acc[mt][nt][tt];
                        out[rowoff + (unsigned)j] = sqrtf(fmaxf(d2, 0.0f));
                    }
                }
            }
        }
    }
}

extern "C" void kernel_launch(void* const* d_in, const int* in_sizes, int n_in,
                              void* d_out, int out_size, void* d_ws, size_t ws_size,
                              hipStream_t stream) {
    const float* x = (const float*)d_in[0];
    float* out = (float*)d_out;

    // Workspace layout: [0, 4MB) bf16 copy of x; then 16KB of fp32 row norms.
    __bf16* xb = (__bf16*)d_ws;
    float* sq  = (float*)((char*)d_ws + (size_t)N * D * sizeof(__bf16));

    prep_kernel<<<N / 4, 256, 0, stream>>>(x, xb, sq);

    // Grid: bi in [0,32) x bj in [0, 2*bi+2) -> sum = 32^2 + 32 = 1056 blocks
    int nblocks = 32 * 32 + 32;  // 1056
    pairdist_kernel<<<nblocks, 256, 0, stream>>>(xb, sq, out);
}

// Round 4
// 80.465 us; speedup vs baseline: 1.2351x; 1.1273x over previous
//
#include <hip/hip_runtime.h>
#include <hip/hip_bf16.h>
#include <stdint.h>

#define N 4096
#define D 512
#define TILE 128
#define BK 128           // fp8 bytes (=elems) per K-chunk
#define KITERS (D / BK)  // 4
#define NB (N / TILE)    // 32

typedef float f32x4 __attribute__((ext_vector_type(4)));
typedef int   i32x8 __attribute__((ext_vector_type(8)));
typedef int   i32x4 __attribute__((ext_vector_type(4)));

// ---------------------------------------------------------------------------
// Kernel 1: fp32 -> fp8 e4m3 (OCP) conversion + fp32 row squared-norms.
// One wave per row: 512 elems / 64 lanes = 8 elems/lane (one 8B store).
// Norms are exact fp32; only the Gram term carries fp8 error.
// ---------------------------------------------------------------------------
__global__ __launch_bounds__(256) void prep_kernel(const float* __restrict__ x,
                                                   unsigned char* __restrict__ xq,
                                                   float* __restrict__ sq) {
    int row  = blockIdx.x * 4 + (threadIdx.x >> 6);
    int lane = threadIdx.x & 63;
    const float* xr = x + (size_t)row * D + lane * 8;
    float4 v0 = *reinterpret_cast<const float4*>(xr);
    float4 v1 = *reinterpret_cast<const float4*>(xr + 4);

    // v_cvt_pk_fp8_f32: packs fp8(a),fp8(b) into low/high half of dst word.
    int w0 = __builtin_amdgcn_cvt_pk_fp8_f32(v0.x, v0.y, 0, false);
    w0     = __builtin_amdgcn_cvt_pk_fp8_f32(v0.z, v0.w, w0, true);
    int w1 = __builtin_amdgcn_cvt_pk_fp8_f32(v1.x, v1.y, 0, false);
    w1     = __builtin_amdgcn_cvt_pk_fp8_f32(v1.z, v1.w, w1, true);
    reinterpret_cast<int2*>(xq + (size_t)row * D)[lane] = make_int2(w0, w1);

    float s = v0.x * v0.x + v0.y * v0.y + v0.z * v0.z + v0.w * v0.w +
              v1.x * v1.x + v1.y * v1.y + v1.z * v1.z + v1.w * v1.w;
    #pragma unroll
    for (int off = 32; off > 0; off >>= 1) s += __shfl_down(s, off);
    if (lane == 0) sq[row] = s;
}

// ---------------------------------------------------------------------------
// Kernel 2: lower-triangle Gram via MX-scaled fp8 MFMA (K=128, unit scales)
// + fused distance epilogue. 128x128 tile, 4 waves each owning 64x64.
// - 4 K-iters (vs 16 for bf16 BK=32): 4x fewer barrier drains.
// - Row stride 128 B == 32 banks; glds forces contiguous LDS placement, so
//   we XOR-swizzle the GLOBAL source address per lane: LDS slot (row, chunk)
//   holds global 16B-chunk (chunk ^ (row&7)). Fragment reads then hit all 8
//   four-bank groups evenly -> LDS reads at the 8-clk/b128 BW floor
//   (unswizzled would be 16-way on 2 groups = 2x penalty; R1/R3's 64B-stride
//   bf16 layout had the same 2x penalty).
// ---------------------------------------------------------------------------
__global__ __launch_bounds__(256, 2) void pairdist_kernel(const unsigned char* __restrict__ xq,
                                                          const float* __restrict__ sq,
                                                          float* __restrict__ out) {
    __shared__ __align__(16) unsigned char As[TILE * BK];  // 16 KB
    __shared__ __align__(16) unsigned char Bs[TILE * BK];  // 16 KB

    // Linear block id -> (bi, bj) with bj <= bi (528 lower-triangular pairs)
    int t  = blockIdx.x;
    int bi = (int)((sqrtf(8.0f * (float)t + 1.0f) - 1.0f) * 0.5f);
    while ((bi + 1) * (bi + 2) / 2 <= t) bi++;
    while (bi * (bi + 1) / 2 > t) bi--;
    int bj = t - bi * (bi + 1) / 2;

    int tid  = threadIdx.x;
    int w    = tid >> 6;        // wave 0..3
    int lane = tid & 63;
    int quad = lane >> 4;       // 0..3
    int lr   = lane & 15;       // 0..15
    int wm   = w >> 1;          // wave row (0..1) -> 64 rows
    int wn   = w & 1;           // wave col (0..1) -> 64 cols

    f32x4 acc[4][4];
    #pragma unroll
    for (int mt = 0; mt < 4; mt++)
        #pragma unroll
        for (int nt = 0; nt < 4; nt++)
            acc[mt][nt] = (f32x4)0.0f;

    // Staging: wave w stages rows [w*32, w*32+32) of each 128x128B panel via
    // 4 glds (8 rows each). lane l -> row l>>3, chunk l&7 in LDS; source
    // chunk = (l&7) ^ (l>>3)  (row&7 == l>>3), implementing the XOR swizzle.
    int srow   = lane >> 3;                 // 0..7
    int schunk = lane & 7;                  // 16B chunk
    int sw     = ((schunk ^ srow) << 4);    // swizzled byte offset in row
    const unsigned char* ga = xq + (size_t)(bi * TILE + w * 32 + srow) * D + sw;
    const unsigned char* gb = xq + (size_t)(bj * TILE + w * 32 + srow) * D + sw;
    unsigned char* la = As + w * 32 * BK;   // wave-uniform LDS bases
    unsigned char* lb = Bs + w * 32 * BK;

    for (int k0 = 0; k0 < D; k0 += BK) {
        __syncthreads();   // prev iter's ds_reads done before overwrite
        #pragma unroll
        for (int g = 0; g < 4; g++) {
            __builtin_amdgcn_global_load_lds(
                (const __attribute__((address_space(1))) void*)(ga + k0 + (size_t)g * 8 * D),
                (__attribute__((address_space(3))) void*)(la + g * 8 * BK), 16, 0, 0);
            __builtin_amdgcn_global_load_lds(
                (const __attribute__((address_space(1))) void*)(gb + k0 + (size_t)g * 8 * D),
                (__attribute__((address_space(3))) void*)(lb + g * 8 * BK), 16, 0, 0);
        }
        __syncthreads();   // drains vmcnt(0): staging visible

        // Fragment layout (16x16x128 f8f6f4): lane holds A[m=lr][k=quad*32+j],
        // 32 B = 2 x b128. Swizzle: global chunk m lives at LDS chunk
        // m ^ (lr&7); chunks 2q and 2q+1 -> c0 and c0^1.
        int c0 = (((2 * quad) ^ (lr & 7)) << 4);
        int c1 = c0 ^ 16;
        i32x8 af[4], bfr[4];
        #pragma unroll
        for (int mt = 0; mt < 4; mt++) {
            const unsigned char* rb = As + (wm * 64 + mt * 16 + lr) * BK;
            i32x4 lo = *reinterpret_cast<const i32x4*>(rb + c0);
            i32x4 hi = *reinterpret_cast<const i32x4*>(rb + c1);
            af[mt][0] = lo[0]; af[mt][1] = lo[1]; af[mt][2] = lo[2]; af[mt][3] = lo[3];
            af[mt][4] = hi[0]; af[mt][5] = hi[1]; af[mt][6] = hi[2]; af[mt][7] = hi[3];
        }
        #pragma unroll
        for (int nt = 0; nt < 4; nt++) {
            const unsigned char* rb = Bs + (wn * 64 + nt * 16 + lr) * BK;
            i32x4 lo = *reinterpret_cast<const i32x4*>(rb + c0);
            i32x4 hi = *reinterpret_cast<const i32x4*>(rb + c1);
            bfr[nt][0] = lo[0]; bfr[nt][1] = lo[1]; bfr[nt][2] = lo[2]; bfr[nt][3] = lo[3];
            bfr[nt][4] = hi[0]; bfr[nt][5] = hi[1]; bfr[nt][6] = hi[2]; bfr[nt][7] = hi[3];
        }

        #pragma unroll
        for (int mt = 0; mt < 4; mt++)
            #pragma unroll
            for (int nt = 0; nt < 4; nt++)
                acc[mt][nt] = __builtin_amdgcn_mfma_scale_f32_16x16x128_f8f6f4(
                    af[mt], bfr[nt], acc[mt][nt],
                    0, 0,                 // cbsz=0 (A fp8 e4m3), blgp=0 (B fp8 e4m3)
                    0, 0x7F7F7F7F,        // A scale: e8m0 127 = x1.0
                    0, 0x7F7F7F7F);       // B scale: x1.0
    }

    // Epilogue: D[m][n] at lane: n = lane&15, m = quad*4 + reg (shape-
    // determined C/D layout, m127/m128 — same as 16x16 bf16).
    int ibase = bi * TILE + wm * 64;
    int jbase = bj * TILE + wn * 64;

    float sqi[4][4], sqj[4];
    #pragma unroll
    for (int mt = 0; mt < 4; mt++)
        #pragma unroll
        for (int tt = 0; tt < 4; tt++)
            sqi[mt][tt] = sq[ibase + mt * 16 + quad * 4 + tt];
    #pragma unroll
    for (int nt = 0; nt < 4; nt++)
        sqj[nt] = sq[jbase + nt * 16 + lr];

    if (bi != bj) {
        // Fully-below-diagonal block: all j < i guaranteed -> no predicate
        #pragma unroll
        for (int mt = 0; mt < 4; mt++) {
            #pragma unroll
            for (int tt = 0; tt < 4; tt++) {
                int i = ibase + mt * 16 + quad * 4 + tt;
                unsigned rowoff = (unsigned)(i * (i - 1) / 2);
                #pragma unroll
                for (int nt = 0; nt < 4; nt++) {
                    int j = jbase + nt * 16 + lr;
                    float d2 = sqi[mt][tt] + sqj[nt] - 2.0f * acc[mt][nt][tt];
                    out[rowoff + (unsigned)j] = sqrtf(fmaxf(d2, 0.0f));
                }
            }
        }
    } else {
        #pragma unroll
        for (int mt = 0; mt < 4; mt++) {
            #pragma unroll
            for (int tt = 0; tt < 4; tt++) {
                int i = ibase + mt * 16 + quad * 4 + tt;
                unsigned rowoff = (unsigned)(i * (i - 1) / 2);
                #pragma unroll
                for (int nt = 0; nt < 4; nt++) {
                    int j = jbase + nt * 16 + lr;
                    if (j < i) {
                        float d2 = sqi[mt][tt] + sqj[nt] - 2.0f * acc[mt][nt][tt];
                        out[rowoff + (unsigned)j] = sqrtf(fmaxf(d2, 0.0f));
                    }
                }
            }
        }
    }
}

extern "C" void kernel_launch(void* const* d_in, const int* in_sizes, int n_in,
                              void* d_out, int out_size, void* d_ws, size_t ws_size,
                              hipStream_t stream) {
    const float* x = (const float*)d_in[0];
    float* out = (float*)d_out;

    // Workspace layout: [0, 2MB) fp8 copy of x; then 16KB of fp32 row norms.
    unsigned char* xq = (unsigned char*)d_ws;
    float* sq = (float*)((char*)d_ws + (size_t)N * D);

    prep_kernel<<<N / 4, 256, 0, stream>>>(x, xq, sq);

    int nblocks = NB * (NB + 1) / 2;  // 528 lower-triangular block pairs
    pairdist_kernel<<<nblocks, 256, 0, stream>>>(xq, sq, out);
}